// Round 7
// baseline (237.479 us; speedup 1.0000x reference)
//
#include <hip/hip_runtime.h>
#include <hip/hip_bf16.h>
#include <math.h>

#define BB 16
#define COUTC 64
#define HH 256
#define WWD 256
#define NBLK (BB*HH)          // 4096 row-blocks
#define NPIX (BB*HH*WWD)      // 1,048,576 pixels
#define YTOT ((size_t)NPIX*COUTC)   // 67,108,864 y elements
#define PLANE_SH ((size_t)NPIX*8)   // shorts per 16B-chunk plane of A

typedef __attribute__((ext_vector_type(8))) short short8;
typedef __attribute__((ext_vector_type(4))) float f32x4;
typedef __attribute__((ext_vector_type(4))) unsigned short us4;
typedef __attribute__((ext_vector_type(8))) unsigned short us8;

__device__ __forceinline__ unsigned short f2bf(float f) {
    __hip_bfloat16 h = __float2bfloat16(f);
    return __builtin_bit_cast(unsigned short, h);
}
__device__ __forceinline__ float bf2f(unsigned short u) {
    unsigned v = (unsigned)u << 16;
    return __builtin_bit_cast(float, v);
}

// ---------------------------------------------------------------------------
// Kernel A: offset conv + deformable gather + pack.  One block per (b,h) row.
// No MFMA state, 10.4 KB LDS -> high occupancy.  Output: A-matrix as 8
// chunk-planes of 16 B/px (total 128 B/px = 128 MiB).
// K-layout: k0..26 = xn (pairs w_conv), k32..58 = taps (pairs w_dcn).
// ---------------------------------------------------------------------------
__global__ __launch_bounds__(256) void gather_kernel(
    const float* __restrict__ x,
    const float* __restrict__ w_off,
    const float* __restrict__ b_off,
    unsigned short* __restrict__ Ap)
{
    __shared__ __align__(16) unsigned short xr[5*260*4];   // bf16 [5][260][4]

    const int tid = threadIdx.x;
    const int bid = blockIdx.x;
    const int swz = (bid & 7) * 512 + (bid >> 3);   // XCD-bijective
    const int b = swz >> 8;
    const int h = swz & 255;
    const int w = tid;
    const float* xb = x + (size_t)b * (3*HH*WWD);

    // --- stage x window rows h-2..h+2, cols -2..257, 3ch (coalesced) ------
    #pragma unroll
    for (int ry = 0; ry < 5; ++ry) {
        const int rr = h - 2 + ry;
        const bool rok = (rr >= 0) && (rr < HH);
        #pragma unroll
        for (int cb = 0; cb < 2; ++cb) {
            const int cx = cb*256 + tid;
            if (cx < 260) {
                const int xx = cx - 2;
                const bool ok = rok && (xx >= 0) && (xx < WWD);
                float f0 = ok ? xb[0*(HH*WWD) + rr*WWD + xx] : 0.f;
                float f1 = ok ? xb[1*(HH*WWD) + rr*WWD + xx] : 0.f;
                float f2 = ok ? xb[2*(HH*WWD) + rr*WWD + xx] : 0.f;
                us4 v = { f2bf(f0), f2bf(f1), f2bf(f2), 0 };
                *(us4*)(xr + (ry*260 + cx)*4) = v;
            }
        }
    }
    __syncthreads();

    // --- xn from LDS (3 channels per ds_read_b64) -------------------------
    us4 xnv[3][3];
    #pragma unroll
    for (int dy = 0; dy < 3; ++dy)
        #pragma unroll
        for (int dx = 0; dx < 3; ++dx)
            xnv[dy][dx] = *(const us4*)(xr + ((dy+1)*260 + (w + dx + 1))*4);

    float xn[3][3][3];
    #pragma unroll
    for (int dy = 0; dy < 3; ++dy)
        #pragma unroll
        for (int dx = 0; dx < 3; ++dx) {
            xn[0][dy][dx] = bf2f(xnv[dy][dx][0]);
            xn[1][dy][dx] = bf2f(xnv[dy][dx][1]);
            xn[2][dy][dx] = bf2f(xnv[dy][dx][2]);
        }

    // --- offset conv (weights wave-uniform -> s_load) ---------------------
    float off[18];
    #pragma unroll
    for (int j = 0; j < 18; ++j) off[j] = b_off[j];
    #pragma unroll
    for (int c = 0; c < 3; ++c)
        #pragma unroll
        for (int ky = 0; ky < 3; ++ky)
            #pragma unroll
            for (int kx = 0; kx < 3; ++kx) {
                float v = xn[c][ky][kx];
                #pragma unroll
                for (int j = 0; j < 18; ++j)
                    off[j] = fmaf(v, w_off[((j*3 + c)*3 + ky)*3 + kx], off[j]);
            }

    // --- deformable bilinear taps from LDS window (exact global fallback) -
    float taps[9][3];
    #pragma unroll
    for (int k = 0; k < 9; ++k) {
        const int ky = k / 3, kx = k % 3;
        float py = (float)(h + ky - 1) + off[2*k];
        float px = (float)(w + kx - 1) + off[2*k + 1];
        float y0f = floorf(py), x0f = floorf(px);
        float ly = py - y0f, lx = px - x0f;
        float hy = 1.f - ly, hx = 1.f - lx;
        int y0 = (int)y0f, x0 = (int)x0f;
        int y1 = y0 + 1,  x1 = x0 + 1;
        bool vy0 = (y0 >= 0) && (y0 < HH);
        bool vy1 = (y1 >= 0) && (y1 < HH);
        bool vx0 = (x0 >= 0) && (x0 < WWD);
        bool vx1 = (x1 >= 0) && (x1 < WWD);
        float w00 = (vy0 && vx0) ? hy*hx : 0.f;
        float w01 = (vy0 && vx1) ? hy*lx : 0.f;
        float w10 = (vy1 && vx0) ? ly*hx : 0.f;
        float w11 = (vy1 && vx1) ? ly*lx : 0.f;

        const int wy = y0 - (h - 2);
        if (__builtin_expect(wy >= 0 && wy <= 3 && x0 >= -2 && x0 <= 256, 1)) {
            const int i00 = (wy*260 + (x0 + 2)) * 4;
            us4 c00 = *(const us4*)(xr + i00);
            us4 c01 = *(const us4*)(xr + i00 + 4);
            us4 c10 = *(const us4*)(xr + i00 + 1040);
            us4 c11 = *(const us4*)(xr + i00 + 1044);
            #pragma unroll
            for (int c = 0; c < 3; ++c)
                taps[k][c] = w00*bf2f(c00[c]) + w01*bf2f(c01[c])
                           + w10*bf2f(c10[c]) + w11*bf2f(c11[c]);
        } else {
            int yc0 = min(max(y0, 0), HH-1),  yc1 = min(max(y1, 0), HH-1);
            int xc0 = min(max(x0, 0), WWD-1), xc1 = min(max(x1, 0), WWD-1);
            int i00 = yc0*WWD + xc0, i01 = yc0*WWD + xc1;
            int i10 = yc1*WWD + xc0, i11 = yc1*WWD + xc1;
            #pragma unroll
            for (int c = 0; c < 3; ++c) {
                const float* xc = xb + c*(HH*WWD);
                taps[k][c] = w00*xc[i00] + w01*xc[i01] + w10*xc[i10] + w11*xc[i11];
            }
        }
    }

    // --- pack u[64] and store 8 chunk-planes (coalesced 16B/lane) ---------
    unsigned short u[64];
    #pragma unroll
    for (int c = 0; c < 3; ++c)
        #pragma unroll
        for (int ky = 0; ky < 3; ++ky)
            #pragma unroll
            for (int kx = 0; kx < 3; ++kx)
                u[c*9 + ky*3 + kx] = xnv[ky][kx][c];
    #pragma unroll
    for (int k = 27; k < 32; ++k) u[k] = 0;
    #pragma unroll
    for (int c = 0; c < 3; ++c)
        #pragma unroll
        for (int kt = 0; kt < 9; ++kt)
            u[32 + c*9 + kt] = f2bf(taps[kt][c]);
    #pragma unroll
    for (int k = 59; k < 64; ++k) u[k] = 0;

    const size_t px = (size_t)swz * 256 + (size_t)w;
    #pragma unroll
    for (int c8 = 0; c8 < 8; ++c8) {
        uint4 v;
        v.x = (unsigned)u[c8*8+0] | ((unsigned)u[c8*8+1] << 16);
        v.y = (unsigned)u[c8*8+2] | ((unsigned)u[c8*8+3] << 16);
        v.z = (unsigned)u[c8*8+4] | ((unsigned)u[c8*8+5] << 16);
        v.w = (unsigned)u[c8*8+6] | ((unsigned)u[c8*8+7] << 16);
        *(uint4*)(Ap + (size_t)c8*PLANE_SH + px*8) = v;
    }
}

// ---------------------------------------------------------------------------
// Kernel B: streaming GEMM  [256px x 64k] @ [64k x 64ch], A from global
// planes straight to VGPR fragments, wT in 8KB LDS, register epilogue.
// ---------------------------------------------------------------------------
template<bool BF16Y>
__global__ __launch_bounds__(256) void gemm_kernel(
    const unsigned short* __restrict__ Ap,
    const float* __restrict__ w_dcn,
    const float* __restrict__ w_conv,
    const float* __restrict__ b_conv,
    float* __restrict__ outf,
    unsigned short* __restrict__ yws,
    float* __restrict__ psum,     // [64][NBLK]
    float* __restrict__ psq)      // [64][NBLK]
{
    __shared__ __align__(16) char wtp[8192];
    __shared__ float l2s[256], l2q[256];

    const int tid = threadIdx.x;
    const int bid = blockIdx.x;
    const int swz = (bid & 7) * 512 + (bid >> 3);
    const int b = swz >> 8;
    const int h = swz & 255;
    const int l   = tid & 63;
    const int wv  = tid >> 6;
    const int g   = l >> 4;
    const int r15 = l & 15;

    // --- build wT[n][k] bf16 (w_conv k0..26 | w_dcn k32..58), swizzled ----
    {
        const int n = tid >> 2, kb0 = (tid & 3) * 16;
        unsigned short tmp[16];
        #pragma unroll
        for (int j = 0; j < 16; ++j) {
            int k = kb0 + j;
            float v = 0.f;
            if (k < 27)                  v = w_conv[n*27 + k];
            else if (k >= 32 && k < 59)  v = w_dcn[n*27 + (k - 32)];
            tmp[j] = f2bf(v);
        }
        #pragma unroll
        for (int c = 0; c < 2; ++c) {
            int chunk = (kb0 >> 3) + c;
            uint4 v;
            v.x = (unsigned)tmp[c*8+0] | ((unsigned)tmp[c*8+1] << 16);
            v.y = (unsigned)tmp[c*8+2] | ((unsigned)tmp[c*8+3] << 16);
            v.z = (unsigned)tmp[c*8+4] | ((unsigned)tmp[c*8+5] << 16);
            v.w = (unsigned)tmp[c*8+6] | ((unsigned)tmp[c*8+7] << 16);
            *(uint4*)(wtp + n*128 + ((chunk ^ (n & 7)) << 4)) = v;
        }
    }
    __syncthreads();

    // --- A fragments straight from global planes --------------------------
    const size_t pxb = (size_t)swz * 256;
    short8 a[2][4];
    #pragma unroll
    for (int ks = 0; ks < 2; ++ks)
        #pragma unroll
        for (int mt = 0; mt < 4; ++mt)
            a[ks][mt] = *(const short8*)(Ap + (size_t)(ks*4 + g)*PLANE_SH
                                            + (pxb + wv*64 + mt*16 + r15)*8);

    // --- sequential nt-tiles + register epilogue --------------------------
    #pragma unroll
    for (int nt = 0; nt < 4; ++nt) {
        const int n = nt*16 + r15;
        short8 b0 = *(const short8*)(wtp + n*128 + (((0*4 + g) ^ (n & 7)) << 4));
        short8 b1 = *(const short8*)(wtp + n*128 + (((1*4 + g) ^ (n & 7)) << 4));

        f32x4 acc[4];
        #pragma unroll
        for (int mt = 0; mt < 4; ++mt)
            acc[mt] = (f32x4){0.f, 0.f, 0.f, 0.f};
        #pragma unroll
        for (int mt = 0; mt < 4; ++mt)
            acc[mt] = __builtin_amdgcn_mfma_f32_16x16x32_bf16(a[0][mt], b0, acc[mt], 0, 0, 0);
        #pragma unroll
        for (int mt = 0; mt < 4; ++mt)
            acc[mt] = __builtin_amdgcn_mfma_f32_16x16x32_bf16(a[1][mt], b1, acc[mt], 0, 0, 0);

        const float bcv = b_conv[nt*16 + r15];
        float s = 0.f, s2 = 0.f;
        // D layout: ch = nt*16 + r15, px = wv*64 + mt*16 + g*4 + reg
        const size_t base = ((size_t)(b*64 + nt*16 + r15) << 16)
                          + (size_t)h*256 + wv*64 + g*4;
        #pragma unroll
        for (int mt = 0; mt < 4; ++mt) {
            f32x4 v = acc[mt];
            float ox = v.x + bcv, oy = v.y + bcv, oz = v.z + bcv, ow = v.w + bcv;
            s += ox + oy + oz + ow;
            s2 = fmaf(ox, ox, s2); s2 = fmaf(oy, oy, s2);
            s2 = fmaf(oz, oz, s2); s2 = fmaf(ow, ow, s2);
            if (BF16Y) {
                us4 pv = { f2bf(ox), f2bf(oy), f2bf(oz), f2bf(ow) };
                *(us4*)(yws + base + mt*16) = pv;
            } else {
                float4 pv = { ox, oy, oz, ow };
                *(float4*)(outf + base + mt*16) = pv;
            }
        }
        s  += __shfl_xor(s, 16);  s  += __shfl_xor(s, 32);
        s2 += __shfl_xor(s2, 16); s2 += __shfl_xor(s2, 32);
        if (l < 16) {
            l2s[wv*64 + nt*16 + l] = s;
            l2q[wv*64 + nt*16 + l] = s2;
        }
    }
    __syncthreads();
    if (tid < 64) {
        float ts = l2s[tid] + l2s[64+tid] + l2s[128+tid] + l2s[192+tid];
        float tq = l2q[tid] + l2q[64+tid] + l2q[128+tid] + l2q[192+tid];
        psum[tid*NBLK + swz] = ts;
        psq [tid*NBLK + swz] = tq;
    }
}

// ---------------------------------------------------------------------------
// Fallback fused kernel (R4) for small-ws environments.
// ---------------------------------------------------------------------------
template<bool BF16Y>
__global__ __launch_bounds__(256, 4) void dcn_fused_kernel(
    const float* __restrict__ x,
    const float* __restrict__ w_off,
    const float* __restrict__ b_off,
    const float* __restrict__ w_dcn,
    const float* __restrict__ w_conv,
    const float* __restrict__ b_conv,
    float* __restrict__ outf,
    unsigned short* __restrict__ yws,
    float* __restrict__ psum,
    float* __restrict__ psq)
{
    __shared__ __align__(16) char smem[40960];
    char* kbp = smem;
    char* wtp = smem + 32768;

    const int tid = threadIdx.x;
    const int bid = blockIdx.x;
    const int swz = (bid & 7) * 512 + (bid >> 3);
    const int b = swz >> 8;
    const int h = swz & 255;
    const int w = tid;
    const int l   = tid & 63;
    const int wv  = tid >> 6;
    const int g   = l >> 4;
    const int r15 = l & 15;

    const float* xb = x + (size_t)b * (3*HH*WWD);

    float xn[3][3][3];
    #pragma unroll
    for (int c = 0; c < 3; ++c)
        #pragma unroll
        for (int dy = 0; dy < 3; ++dy) {
            int yy = h + dy - 1;
            #pragma unroll
            for (int dx = 0; dx < 3; ++dx) {
                int xx = w + dx - 1;
                bool ok = (yy >= 0) && (yy < HH) && (xx >= 0) && (xx < WWD);
                xn[c][dy][dx] = ok ? xb[c*(HH*WWD) + yy*WWD + xx] : 0.f;
            }
        }

    {
        const int n = tid >> 2, kb0 = (tid & 3) * 16;
        unsigned short tmp[16];
        #pragma unroll
        for (int j = 0; j < 16; ++j) {
            int k = kb0 + j;
            float v = 0.f;
            if (k < 27)                  v = w_conv[n*27 + k];
            else if (k >= 32 && k < 59)  v = w_dcn[n*27 + (k - 32)];
            tmp[j] = f2bf(v);
        }
        #pragma unroll
        for (int c = 0; c < 2; ++c) {
            int chunk = (kb0 >> 3) + c;
            uint4 v;
            v.x = (unsigned)tmp[c*8+0] | ((unsigned)tmp[c*8+1] << 16);
            v.y = (unsigned)tmp[c*8+2] | ((unsigned)tmp[c*8+3] << 16);
            v.z = (unsigned)tmp[c*8+4] | ((unsigned)tmp[c*8+5] << 16);
            v.w = (unsigned)tmp[c*8+6] | ((unsigned)tmp[c*8+7] << 16);
            *(uint4*)(wtp + n*128 + ((chunk ^ (n & 7)) << 4)) = v;
        }
    }

    float off[18];
    #pragma unroll
    for (int j = 0; j < 18; ++j) off[j] = b_off[j];
    #pragma unroll
    for (int c = 0; c < 3; ++c)
        #pragma unroll
        for (int ky = 0; ky < 3; ++ky)
            #pragma unroll
            for (int kx = 0; kx < 3; ++kx) {
                float v = xn[c][ky][kx];
                #pragma unroll
                for (int j = 0; j < 18; ++j)
                    off[j] = fmaf(v, w_off[((j*3 + c)*3 + ky)*3 + kx], off[j]);
            }

    {
        unsigned short u[32];
        #pragma unroll
        for (int c = 0; c < 3; ++c)
            #pragma unroll
            for (int ky = 0; ky < 3; ++ky)
                #pragma unroll
                for (int kx = 0; kx < 3; ++kx)
                    u[c*9 + ky*3 + kx] = f2bf(xn[c][ky][kx]);
        #pragma unroll
        for (int k = 27; k < 32; ++k) u[k] = 0;
        #pragma unroll
        for (int c8 = 0; c8 < 4; ++c8) {
            uint4 v;
            v.x = (unsigned)u[c8*8+0] | ((unsigned)u[c8*8+1] << 16);
            v.y = (unsigned)u[c8*8+2] | ((unsigned)u[c8*8+3] << 16);
            v.z = (unsigned)u[c8*8+4] | ((unsigned)u[c8*8+5] << 16);
            v.w = (unsigned)u[c8*8+6] | ((unsigned)u[c8*8+7] << 16);
            *(uint4*)(kbp + w*128 + ((c8 ^ (w & 7)) << 4)) = v;
        }
    }

    float taps[9][3];
    #pragma unroll
    for (int k = 0; k < 9; ++k) {
        const int ky = k / 3, kx = k % 3;
        float py = (float)(h + ky - 1) + off[2*k];
        float px = (float)(w + kx - 1) + off[2*k + 1];
        float y0f = floorf(py), x0f = floorf(px);
        float ly = py - y0f, lx = px - x0f;
        float hy = 1.f - ly, hx = 1.f - lx;
        int y0 = (int)y0f, x0 = (int)x0f;
        int y1 = y0 + 1,  x1 = x0 + 1;
        bool vy0 = (y0 >= 0) && (y0 < HH);
        bool vy1 = (y1 >= 0) && (y1 < HH);
        bool vx0 = (x0 >= 0) && (x0 < WWD);
        bool vx1 = (x1 >= 0) && (x1 < WWD);
        float w00 = (vy0 && vx0) ? hy*hx : 0.f;
        float w01 = (vy0 && vx1) ? hy*lx : 0.f;
        float w10 = (vy1 && vx0) ? ly*hx : 0.f;
        float w11 = (vy1 && vx1) ? ly*lx : 0.f;
        int yc0 = min(max(y0, 0), HH-1),  yc1 = min(max(y1, 0), HH-1);
        int xc0 = min(max(x0, 0), WWD-1), xc1 = min(max(x1, 0), WWD-1);
        int i00 = yc0*WWD + xc0, i01 = yc0*WWD + xc1;
        int i10 = yc1*WWD + xc0, i11 = yc1*WWD + xc1;
        #pragma unroll
        for (int c = 0; c < 3; ++c) {
            const float* xc = xb + c*(HH*WWD);
            taps[k][c] = w00*xc[i00] + w01*xc[i01] + w10*xc[i10] + w11*xc[i11];
        }
    }

    {
        unsigned short u[32];
        #pragma unroll
        for (int c = 0; c < 3; ++c)
            #pragma unroll
            for (int kt = 0; kt < 9; ++kt)
                u[c*9 + kt] = f2bf(taps[kt][c]);
        #pragma unroll
        for (int k = 27; k < 32; ++k) u[k] = 0;
        #pragma unroll
        for (int c8 = 4; c8 < 8; ++c8) {
            const int j0 = (c8 - 4) * 8;
            uint4 v;
            v.x = (unsigned)u[j0+0] | ((unsigned)u[j0+1] << 16);
            v.y = (unsigned)u[j0+2] | ((unsigned)u[j0+3] << 16);
            v.z = (unsigned)u[j0+4] | ((unsigned)u[j0+5] << 16);
            v.w = (unsigned)u[j0+6] | ((unsigned)u[j0+7] << 16);
            *(uint4*)(kbp + w*128 + ((c8 ^ (w & 7)) << 4)) = v;
        }
    }

    __syncthreads();

    short8 a[2][4];
    #pragma unroll
    for (int ks = 0; ks < 2; ++ks)
        #pragma unroll
        for (int mt = 0; mt < 4; ++mt) {
            int row = wv*64 + mt*16 + r15;
            int chunk = ks*4 + g;
            a[ks][mt] = *(const short8*)(kbp + row*128 + ((chunk ^ (row & 7)) << 4));
        }

    __syncthreads();

    float* l2s = (float*)kbp;
    float* l2q = (float*)(kbp + 1024);

    #pragma unroll
    for (int nt = 0; nt < 4; ++nt) {
        const int n = nt*16 + r15;
        short8 b0 = *(const short8*)(wtp + n*128 + (((0*4 + g) ^ (n & 7)) << 4));
        short8 b1 = *(const short8*)(wtp + n*128 + (((1*4 + g) ^ (n & 7)) << 4));

        f32x4 acc[4];
        #pragma unroll
        for (int mt = 0; mt < 4; ++mt)
            acc[mt] = (f32x4){0.f, 0.f, 0.f, 0.f};
        #pragma unroll
        for (int mt = 0; mt < 4; ++mt)
            acc[mt] = __builtin_amdgcn_mfma_f32_16x16x32_bf16(a[0][mt], b0, acc[mt], 0, 0, 0);
        #pragma unroll
        for (int mt = 0; mt < 4; ++mt)
            acc[mt] = __builtin_amdgcn_mfma_f32_16x16x32_bf16(a[1][mt], b1, acc[mt], 0, 0, 0);

        const float bcv = b_conv[nt*16 + r15];
        float s = 0.f, s2 = 0.f;
        const size_t base = ((size_t)(b*64 + nt*16 + r15) << 16)
                          + (size_t)h*256 + wv*64 + g*4;
        #pragma unroll
        for (int mt = 0; mt < 4; ++mt) {
            f32x4 v = acc[mt];
            float ox = v.x + bcv, oy = v.y + bcv, oz = v.z + bcv, ow = v.w + bcv;
            s += ox + oy + oz + ow;
            s2 = fmaf(ox, ox, s2); s2 = fmaf(oy, oy, s2);
            s2 = fmaf(oz, oz, s2); s2 = fmaf(ow, ow, s2);
            if (BF16Y) {
                us4 pv = { f2bf(ox), f2bf(oy), f2bf(oz), f2bf(ow) };
                *(us4*)(yws + base + mt*16) = pv;
            } else {
                float4 pv = { ox, oy, oz, ow };
                *(float4*)(outf + base + mt*16) = pv;
            }
        }
        s  += __shfl_xor(s, 16);  s  += __shfl_xor(s, 32);
        s2 += __shfl_xor(s2, 16); s2 += __shfl_xor(s2, 32);
        if (l < 16) {
            l2s[wv*64 + nt*16 + l] = s;
            l2q[wv*64 + nt*16 + l] = s2;
        }
    }
    __syncthreads();
    if (tid < 64) {
        float ts = l2s[tid] + l2s[64+tid] + l2s[128+tid] + l2s[192+tid];
        float tq = l2q[tid] + l2q[64+tid] + l2q[128+tid] + l2q[192+tid];
        psum[tid*NBLK + swz] = ts;
        psq [tid*NBLK + swz] = tq;
    }
}

// ---------------------------------------------------------------------------
// Kernel 2: reduce partials -> per-channel scale/shift (deterministic order)
// ---------------------------------------------------------------------------
__global__ __launch_bounds__(256) void bn_stats_kernel(
    const float* __restrict__ psum,
    const float* __restrict__ psq,
    const float* __restrict__ gamma,
    const float* __restrict__ beta,
    float* __restrict__ ss)
{
    __shared__ float rs[256], rq[256];
    const int ch = blockIdx.x, tid = threadIdx.x;
    float s = 0.f, s2 = 0.f;
    for (int j = tid; j < NBLK; j += 256) {
        s  += psum[ch*NBLK + j];
        s2 += psq [ch*NBLK + j];
    }
    rs[tid] = s; rq[tid] = s2;
    __syncthreads();
    for (int st = 128; st > 0; st >>= 1) {
        if (tid < st) { rs[tid] += rs[tid + st]; rq[tid] += rq[tid + st]; }
        __syncthreads();
    }
    if (tid == 0) {
        const float N = (float)NPIX;
        float mean = rs[0] / N;
        float var  = rq[0] / N - mean*mean;
        float rstd = rsqrtf(var + 1e-5f);
        float sc   = gamma[ch] * rstd;
        ss[ch]      = sc;
        ss[64 + ch] = beta[ch] - mean * sc;
    }
}

// ---------------------------------------------------------------------------
// Kernel 3a (bf16 path): read y bf16 from ws, affine + SiLU, write fp32 out
// ---------------------------------------------------------------------------
__global__ __launch_bounds__(256) void bn_silu_bf16_kernel(
    const unsigned short* __restrict__ yws,
    float* __restrict__ out,
    const float* __restrict__ ss)
{
    __shared__ float sc[64], sh[64];
    if (threadIdx.x < 64) {
        sc[threadIdx.x] = ss[threadIdx.x];
        sh[threadIdx.x] = ss[64 + threadIdx.x];
    }
    __syncthreads();
    const int total8 = (int)(YTOT / 8);
    for (int i = blockIdx.x*256 + threadIdx.x; i < total8; i += gridDim.x*256) {
        us8 v = *(const us8*)(yws + (size_t)i*8);
        const int o = (i >> 13) & 63;
        const float a = sc[o], t = sh[o];
        float e[8];
        #pragma unroll
        for (int j = 0; j < 8; ++j) {
            float z = fmaf(bf2f(v[j]), a, t);
            e[j] = z / (1.f + __expf(-z));
        }
        float4 r0 = { e[0], e[1], e[2], e[3] };
        float4 r1 = { e[4], e[5], e[6], e[7] };
        *(float4*)(out + (size_t)i*8)     = r0;
        *(float4*)(out + (size_t)i*8 + 4) = r1;
    }
}

// ---------------------------------------------------------------------------
// Kernel 3b (fallback): in-place affine + SiLU over fp32 d_out
// ---------------------------------------------------------------------------
__global__ __launch_bounds__(256) void bn_silu_kernel(
    float* __restrict__ y,
    const float* __restrict__ ss)
{
    __shared__ float sc[64], sh[64];
    if (threadIdx.x < 64) {
        sc[threadIdx.x] = ss[threadIdx.x];
        sh[threadIdx.x] = ss[64 + threadIdx.x];
    }
    __syncthreads();
    float4* y4 = (float4*)y;
    const int total4 = (int)(YTOT / 4);
    for (int i = blockIdx.x*256 + threadIdx.x; i < total4; i += gridDim.x*256) {
        float4 v = y4[i];
        const int o = (i >> 14) & 63;
        const float a = sc[o], t = sh[o];
        float z;
        z = fmaf(v.x, a, t); v.x = z / (1.f + __expf(-z));
        z = fmaf(v.y, a, t); v.y = z / (1.f + __expf(-z));
        z = fmaf(v.z, a, t); v.z = z / (1.f + __expf(-z));
        z = fmaf(v.w, a, t); v.w = z / (1.f + __expf(-z));
        y4[i] = v;
    }
}

// ---------------------------------------------------------------------------
extern "C" void kernel_launch(void* const* d_in, const int* in_sizes, int n_in,
                              void* d_out, int out_size, void* d_ws, size_t ws_size,
                              hipStream_t stream) {
    const float* x      = (const float*)d_in[0];
    const float* w_off  = (const float*)d_in[1];
    const float* b_off  = (const float*)d_in[2];
    const float* w_dcn  = (const float*)d_in[3];
    const float* w_conv = (const float*)d_in[4];
    const float* b_conv = (const float*)d_in[5];
    const float* gamma  = (const float*)d_in[6];
    const float* beta   = (const float*)d_in[7];
    float* out = (float*)d_out;

    // A-matrix: 64 bf16 k-values = 128 B per pixel (8 planes x 16 B).
    const size_t aBytes    = (size_t)NPIX * 128;             // 128 MiB
    const size_t yBytes    = YTOT * 2;                       // 128 MiB bf16 y
    const size_t statBytes = 2*(size_t)64*NBLK*4 + 512;

    if (ws_size >= aBytes + yBytes + statBytes) {
        // split path: gather -> A ; GEMM -> bf16 y ; stats ; silu
        unsigned short* Ap  = (unsigned short*)d_ws;
        unsigned short* yws = (unsigned short*)((char*)d_ws + aBytes);
        float* psum = (float*)((char*)d_ws + aBytes + yBytes);
        float* psq  = psum + 64*NBLK;
        float* ss   = psq  + 64*NBLK;
        gather_kernel<<<NBLK, 256, 0, stream>>>(x, w_off, b_off, Ap);
        gemm_kernel<true><<<NBLK, 256, 0, stream>>>(
            Ap, w_dcn, w_conv, b_conv, nullptr, yws, psum, psq);
        bn_stats_kernel<<<64, 256, 0, stream>>>(psum, psq, gamma, beta, ss);
        bn_silu_bf16_kernel<<<2048, 256, 0, stream>>>(yws, out, ss);
    } else if (ws_size >= aBytes + statBytes) {
        // split path, fp32 y staged in d_out, normalized in place
        unsigned short* Ap  = (unsigned short*)d_ws;
        float* psum = (float*)((char*)d_ws + aBytes);
        float* psq  = psum + 64*NBLK;
        float* ss   = psq  + 64*NBLK;
        gather_kernel<<<NBLK, 256, 0, stream>>>(x, w_off, b_off, Ap);
        gemm_kernel<false><<<NBLK, 256, 0, stream>>>(
            Ap, w_dcn, w_conv, b_conv, out, nullptr, psum, psq);
        bn_stats_kernel<<<64, 256, 0, stream>>>(psum, psq, gamma, beta, ss);
        bn_silu_kernel<<<2048, 256, 0, stream>>>(out, ss);
    } else {
        // fused fallback (R4)
        float* psum = (float*)d_ws;
        float* psq  = psum + 64*NBLK;
        float* ss   = psq  + 64*NBLK;
        dcn_fused_kernel<false><<<NBLK, 256, 0, stream>>>(
            x, w_off, b_off, w_dcn, w_conv, b_conv, out, nullptr, psum, psq);
        bn_stats_kernel<<<64, 256, 0, stream>>>(psum, psq, gamma, beta, ss);
        bn_silu_kernel<<<2048, 256, 0, stream>>>(out, ss);
    }
}